// Round 5
// baseline (951.348 us; speedup 1.0000x reference)
//
#include <hip/hip_runtime.h>

// Sinkhorn EMD, B=8, N=2048, eps=0.005, 50 iters.
// R23 = R22 with the scratch-spill bug fixed. R21/R22's regression
// (FETCH +41MB, WRITE +46MB, dur 500->716/732 despite VALUBusy 42->31%)
// was diagnosed via VGPR_Count=64: the 48-reg X/J cache NEVER made it to
// registers. Cause: `odd ? XG[r][c] : XF[r][c]` lowers as a POINTER
// select between the arrays -> SROA defeated -> both arrays in scratch ->
// a ~200cy dependent scratch load in front of every pot gather.
// Fix: loop B processes passes in even/odd PAIRS. The even body touches
// only XF/JF/LpF/pcf, the odd body only XG/JG/LpG/pcg — every array index
// is a compile-time constant, zero runtime selects near the arrays.
// Kept (validated by counters): register-cached sparse lists (bank
// conflicts 3.16M->75K), 4-lane coalesced pot store, dense/sparse split.
// Structure (validated in prior rounds): persistent 256x1024, IC-coherent
// atomics no fences, counter barrier, online exact-LSE passes 0..3, build
// at 4,5, fixed-shift M = own prev log-sum, MARGIN=48, CAP=256.

#define BB 8
#define NN 2048
#define NPASS 100
#define DENSE_PASSES 6
#define RPW 4
#define GRID_BLOCKS 256
#define BLOCKS_PER_BATCH 32
#define TPB 1024
#define CAP 256
#define MARGIN 48.0f

constexpr float EPSV = 0.005f;
constexpr float KS   = EPSV * 0.69314718055994531f; // eps*ln2
constexpr float INVK = 1.0f / KS;
constexpr float C1V  = -EPSV * 7.6246189861593985f; // eps*log(1/2048)
constexpr float C1K  = C1V * INVK;
constexpr float KQ4  = KS * 0.25f;
constexpr float TWOI = 2.0f * INVK;
constexpr float HK   = KS * 0.5f;

__device__ __forceinline__ float fexp2(float x) { return __builtin_amdgcn_exp2f(x); }
__device__ __forceinline__ float flog2(float x) { return __builtin_amdgcn_logf(x); }

__device__ __forceinline__ float cohLoad(const float* p) {
    return __hip_atomic_load(p, __ATOMIC_RELAXED, __HIP_MEMORY_SCOPE_AGENT);
}
__device__ __forceinline__ void cohStore(float* p, float v) {
    __hip_atomic_store(p, v, __ATOMIC_RELAXED, __HIP_MEMORY_SCOPE_AGENT);
}
// 4 consecutive row-pots stored by lanes 0..3 in ONE wave instruction:
// 4x4B contiguous = one 32B sector, proven 32-bit plain-store path.
__device__ __forceinline__ void potStore4(float* p, int lane,
                                          float o0, float o1, float o2, float o3) {
    if (lane < 4) {
        float ov = (lane == 0) ? o0 : (lane == 1) ? o1 : (lane == 2) ? o2 : o3;
        cohStore(p + lane, ov);
    }
}

__device__ __forceinline__ void barrier_sync(int* ctr, int target) {
    __syncthreads();   // drains vmcnt: all waves' cohStores acked at IC
    if (threadIdx.x == 0) {
        __hip_atomic_fetch_add(ctr, 1, __ATOMIC_RELAXED, __HIP_MEMORY_SCOPE_AGENT);
        while (__hip_atomic_load(ctr, __ATOMIC_RELAXED, __HIP_MEMORY_SCOPE_AGENT) < target) {
            __builtin_amdgcn_s_sleep(1);
        }
    }
    __syncthreads();
}

// One sparse half-iteration. ALL array accesses (XA, JA, LP, PCA) use
// literal/unrolled indices only — no runtime selects between arrays.
//  FSH: fallback bitmask shift (0 = f-side, 4 = g-side)
//  PTOFF: sjall offset of the COLUMN points; ROWOFF: of this side's rows.
#define SPARSE_SIDE(PIN, POUT, XA, JA, LP, PCA, FSH, PTOFF, ROWOFF)            \
  {                                                                            \
    float L_[RPW];                                                             \
    _Pragma("unroll")                                                          \
    for (int r = 0; r < RPW; ++r) {                                            \
      const float Mr = LP[r];                                                  \
      float s1 = 0.f;                                                          \
      if (((fbm >> (FSH + r)) & 1) == 0) {                                     \
        int j0 = (int)(JA[r][0] & 0xffffu);                                    \
        int j1 = (int)(JA[r][0] >> 16);                                        \
        int j2 = (int)(JA[r][1] & 0xffffu);                                    \
        int j3 = (int)(JA[r][1] >> 16);                                        \
        float p0 = cohLoad(&PIN[j0]);                                          \
        float p1 = cohLoad(&PIN[j1]);                                          \
        float p2 = cohLoad(&PIN[j2]);                                          \
        float p3 = cohLoad(&PIN[j3]);                                          \
        s1 += fexp2(fminf(fmaf(p0, INVK, XA[r][0]) - Mr, 100.f));              \
        s1 += fexp2(fminf(fmaf(p1, INVK, XA[r][1]) - Mr, 100.f));              \
        s1 += fexp2(fminf(fmaf(p2, INVK, XA[r][2]) - Mr, 100.f));              \
        s1 += fexp2(fminf(fmaf(p3, INVK, XA[r][3]) - Mr, 100.f));              \
      } else {                                                                 \
        float4 dm = sjall[ROWOFF + row0 + r];                                  \
        float qxr = HK*dm.x, qyr = HK*dm.y, qzr = HK*dm.z;                     \
        _Pragma("unroll 1")                                                    \
        for (int c = 0; c < 32; ++c) {                                         \
          int j = c*64 + lane;                                                 \
          float4 d = sjall[PTOFF + j];                                         \
          float aw = fmaf(cohLoad(&PIN[j]), INVK, d.w);                        \
          float x  = fmaf(qxr, d.x, fmaf(qyr, d.y, fmaf(qzr, d.z, aw)));       \
          s1 += fexp2(fminf(x - Mr, 100.f));                                   \
        }                                                                      \
      }                                                                        \
      for (int off = 1; off < 64; off <<= 1) s1 += __shfl_xor(s1, off, 64);    \
      L_[r] = Mr + flog2(fmaxf(s1, 1e-37f));                                   \
    }                                                                          \
    _Pragma("unroll")                                                          \
    for (int r = 0; r < RPW; ++r) LP[r] = L_[r];                               \
    potStore4(&POUT[row0], lane, PCA[0]-KS*L_[0], PCA[1]-KS*L_[1],             \
              PCA[2]-KS*L_[2], PCA[3]-KS*L_[3]);                               \
  }

__global__ void __launch_bounds__(TPB, 4) emd_persist(
    const float* __restrict__ preds, const float* __restrict__ gts,
    float* __restrict__ fpot, float* __restrict__ gpot,
    float* __restrict__ partials, int* __restrict__ bctr, int* __restrict__ gctr,
    float* __restrict__ out)
{
    __shared__ float4 sjall[2 * NN];          // side0=gts, side1=preds
    __shared__ float  sa[NN];                 // staged pots (dense passes only)
    __shared__ float  wred[16];
    __shared__ unsigned short slist[2][64][CAP];

    const int blk  = blockIdx.x;
    const int b    = blk & 7;
    const int rb   = blk >> 3;
    const int wave = threadIdx.x >> 6;
    const int lane = threadIdx.x & 63;
    const int rowL0 = wave * RPW;             // 0..60
    const int row0  = rb * 64 + rowL0;        // global row base for this wave

    const float* pb  = preds + (size_t)b * NN * 3;
    const float* gbp = gts   + (size_t)b * NN * 3;
    float* fb = fpot + (size_t)b * NN;
    float* gb = gpot + (size_t)b * NN;
    int*   bar = bctr + b * 32;

    for (int t = threadIdx.x; t < NN; t += TPB) {
        float gx = gbp[3*t], gy = gbp[3*t+1], gz = gbp[3*t+2];
        float Gx = gx*TWOI, Gy = gy*TWOI, Gz = gz*TWOI;
        sjall[t] = make_float4(Gx, Gy, Gz, -KQ4*(Gx*Gx+Gy*Gy+Gz*Gz));
        float qx = pb[3*t], qy = pb[3*t+1], qz = pb[3*t+2];
        float Qx = qx*TWOI, Qy = qy*TWOI, Qz = qz*TWOI;
        sjall[NN+t] = make_float4(Qx, Qy, Qz, -KQ4*(Qx*Qx+Qy*Qy+Qz*Qz));
    }
    __syncthreads();

    // wave-resident row constants, both sides.
    float qxf[RPW], qyf[RPW], qzf[RPW], pcf[RPW];
    float qxg[RPW], qyg[RPW], qzg[RPW], pcg[RPW];
#pragma unroll
    for (int r = 0; r < RPW; ++r) {
        float4 df = sjall[NN + row0 + r];     // preds rows (f side)
        qxf[r] = HK*df.x; qyf[r] = HK*df.y; qzf[r] = HK*df.z;
        pcf[r] = C1V - KS*df.w;
        float4 dg = sjall[row0 + r];          // gts rows (g side)
        qxg[r] = HK*dg.x; qyg[r] = HK*dg.y; qzg[r] = HK*dg.z;
        pcg[r] = C1V - KS*dg.w;
    }
    float LpF[RPW] = {0,0,0,0}, LpG[RPW] = {0,0,0,0};
    int   cnF[RPW] = {0,0,0,0}, cnG[RPW] = {0,0,0,0};

    // ---------------- Loop A: dense online (0..3) + build (4,5) ----------------
#pragma unroll 1
    for (int pass = 0; pass < DENSE_PASSES; ++pass) {
        const int odd = pass & 1;
        const int colOff = odd ? NN : 0;
        const float* pin  = odd ? fb : gb;
        float*       pout = odd ? gb : fb;

        float qx[RPW], qy[RPW], qz[RPW], pc[RPW], M[RPW], Lr[RPW];
#pragma unroll
        for (int r = 0; r < RPW; ++r) {
            qx[r] = odd ? qxg[r] : qxf[r];
            qy[r] = odd ? qyg[r] : qyf[r];
            qz[r] = odd ? qzg[r] : qzf[r];
            pc[r] = odd ? pcg[r] : pcf[r];
            M[r]  = odd ? LpG[r] : LpF[r];
        }

        for (int t = threadIdx.x; t < NN; t += TPB)
            sa[t] = cohLoad(&pin[t]) * INVK;
        __syncthreads();

        if (pass < 4) {
            // online exact LSE
            float m[RPW], s[RPW];
#pragma unroll
            for (int r = 0; r < RPW; ++r) { m[r] = -1e30f; s[r] = 0.f; }
#pragma unroll 2
            for (int c = 0; c < 32; ++c) {
                float4 d = sjall[colOff + c*64 + lane];
                float aw = d.w + sa[c*64 + lane];
#pragma unroll
                for (int r = 0; r < RPW; ++r) {
                    float x  = fmaf(qx[r], d.x, fmaf(qy[r], d.y, fmaf(qz[r], d.z, aw)));
                    float mn = fmaxf(m[r], x);
                    s[r] = fmaf(s[r], fexp2(m[r]-mn), fexp2(x-mn));
                    m[r] = mn;
                }
            }
#pragma unroll
            for (int r = 0; r < RPW; ++r) {
                float mm = m[r], sv = s[r];
                for (int off = 1; off < 64; off <<= 1) {
                    float mo = __shfl_xor(mm, off, 64);
                    float so = __shfl_xor(sv, off, 64);
                    float mn = fmaxf(mm, mo);
                    sv = fmaf(sv, fexp2(mm-mn), so * fexp2(mo-mn));
                    mm = mn;
                }
                float L = mm + flog2(fmaxf(sv, 1e-37f));
                Lr[r] = L;
                if (odd) LpG[r] = L; else LpF[r] = L;
            }
        } else {
            // build: dense fixed-shift + register-count compaction
            float s[RPW]; int cn[RPW];
#pragma unroll
            for (int r = 0; r < RPW; ++r) { s[r] = 0.f; cn[r] = 0; }
#pragma unroll 1
            for (int c = 0; c < 32; ++c) {
                int j = c*64 + lane;
                float4 d = sjall[colOff + j];
                float aw = d.w + sa[j];
#pragma unroll
                for (int r = 0; r < RPW; ++r) {
                    float x = fmaf(qx[r], d.x, fmaf(qy[r], d.y, fmaf(qz[r], d.z, aw)));
                    s[r] += fexp2(fminf(x - M[r], 100.f));
                    bool pred = (x >= M[r] - MARGIN);
                    unsigned long long mask = __ballot((int)pred);
                    if (pred) {
                        int pos = cn[r] + __popcll(mask & ((1ull << lane) - 1ull));
                        if (pos < CAP) slist[odd][rowL0 + r][pos] = (unsigned short)j;
                    }
                    cn[r] += __popcll(mask);   // wave-uniform
                }
            }
#pragma unroll
            for (int r = 0; r < RPW; ++r) {
                float sv = s[r];
                for (int off = 1; off < 64; off <<= 1) sv += __shfl_xor(sv, off, 64);
                float L = M[r] + flog2(fmaxf(sv, 1e-37f));
                Lr[r] = L;
                if (odd) { LpG[r] = L; cnG[r] = cn[r]; }
                else     { LpF[r] = L; cnF[r] = cn[r]; }
            }
        }
        potStore4(&pout[row0], lane,
                  pc[0]-KS*Lr[0], pc[1]-KS*Lr[1], pc[2]-KS*Lr[2], pc[3]-KS*Lr[3]);
        barrier_sync(bar, BLOCKS_PER_BATCH * (pass + 1));
    }

    // ---- register fill: cache lists + pass-invariant X = q.d3 + d.w ----
    // Constant indices ONLY (r,c fully unrolled) so SROA keeps these in VGPRs.
    float XF[RPW][4], XG[RPW][4];
    unsigned JF[RPW][2], JG[RPW][2];
    int fbm = 0;  // fallback bitmask: bits 0..3 f-side cnt>CAP, 4..7 g-side
#pragma unroll
    for (int r = 0; r < RPW; ++r) {
        if (cnF[r] > CAP) fbm |= (1 << r);
        if (cnG[r] > CAP) fbm |= (16 << r);
        const int cF = cnF[r] < CAP ? cnF[r] : CAP;
        const int cG = cnG[r] < CAP ? cnG[r] : CAP;
#pragma unroll
        for (int c = 0; c < 4; ++c) {
            const int k = c*64 + lane;
            int jF = (k < cF) ? (int)slist[0][rowL0 + r][k] : 0;
            float4 dF = sjall[jF];
            float xF = fmaf(qxf[r], dF.x, fmaf(qyf[r], dF.y, fmaf(qzf[r], dF.z, dF.w)));
            XF[r][c] = (k < cF) ? xF : -1e30f;
            int jG = (k < cG) ? (int)slist[1][rowL0 + r][k] : 0;
            float4 dG = sjall[NN + jG];
            float xG = fmaf(qxg[r], dG.x, fmaf(qyg[r], dG.y, fmaf(qzg[r], dG.z, dG.w)));
            XG[r][c] = (k < cG) ? xG : -1e30f;
            if ((c & 1) == 0) { JF[r][c>>1] = (unsigned)jF; JG[r][c>>1] = (unsigned)jG; }
            else              { JF[r][c>>1] |= (unsigned)jF << 16; JG[r][c>>1] |= (unsigned)jG << 16; }
        }
    }

    // ---------------- Loop B: sparse passes 6..99, even/odd PAIRED ----------------
    // Even pass p: pin=gb pout=fb, f-side rows (preds @ sjall[NN..]), cols=gts.
    // Odd  pass p+1: pin=fb pout=gb, g-side rows (gts @ sjall[0..]), cols=preds.
#pragma unroll 1
    for (int it = 0; it < (NPASS - DENSE_PASSES) / 2; ++it) {
        SPARSE_SIDE(gb, fb, XF, JF, LpF, pcf, 0, 0, NN);
        barrier_sync(bar, BLOCKS_PER_BATCH * (DENSE_PASSES + 2*it + 1));
        SPARSE_SIDE(fb, gb, XG, JG, LpG, pcg, 4, NN, 0);
        barrier_sync(bar, BLOCKS_PER_BATCH * (DENSE_PASSES + 2*it + 2));
    }

    // ---- dis: sum P*C over f-lists via cached X/j; D = dot3 + d.w ----
    {
        float acc[RPW];
#pragma unroll
        for (int r = 0; r < RPW; ++r) {
            const float bb2 = C1K - LpF[r];
            const float pn  = pcf[r] - C1V;    // |p|^2 (scaled)
            float aa = 0.f;
            if (((fbm >> r) & 1) == 0) {
                int j0 = (int)(JF[r][0] & 0xffffu);
                int j1 = (int)(JF[r][0] >> 16);
                int j2 = (int)(JF[r][1] & 0xffffu);
                int j3 = (int)(JF[r][1] >> 16);
                float p0 = cohLoad(&gb[j0]);
                float p1 = cohLoad(&gb[j1]);
                float p2 = cohLoad(&gb[j2]);
                float p3 = cohLoad(&gb[j3]);
                float e0 = fexp2(fminf(fmaf(p0, INVK, XF[r][0]) + bb2, 80.f));
                float e1 = fexp2(fminf(fmaf(p1, INVK, XF[r][1]) + bb2, 80.f));
                float e2 = fexp2(fminf(fmaf(p2, INVK, XF[r][2]) + bb2, 80.f));
                float e3 = fexp2(fminf(fmaf(p3, INVK, XF[r][3]) + bb2, 80.f));
                aa = fmaf(e0, fmaf(-KS, XF[r][0], pn), aa);  // e==0 kills sentinels
                aa = fmaf(e1, fmaf(-KS, XF[r][1], pn), aa);
                aa = fmaf(e2, fmaf(-KS, XF[r][2], pn), aa);
                aa = fmaf(e3, fmaf(-KS, XF[r][3], pn), aa);
            } else {
                float4 dm = sjall[NN + row0 + r];
                float qxr = HK*dm.x, qyr = HK*dm.y, qzr = HK*dm.z;
#pragma unroll 1
                for (int c = 0; c < 32; ++c) {
                    int j = c*64 + lane;
                    float4 d = sjall[j];
                    float aw = fmaf(cohLoad(&gb[j]), INVK, d.w);
                    float dot = fmaf(qxr, d.x, fmaf(qyr, d.y, qzr*d.z));
                    float y   = dot + aw + bb2;
                    float e   = fexp2(fminf(y, 80.f));
                    aa = fmaf(e, fmaf(-KS, dot, pn - KS*d.w), aa);
                }
            }
            acc[r] = aa;
        }
        float tot = acc[0] + acc[1] + acc[2] + acc[3];
        for (int off = 1; off < 64; off <<= 1) tot += __shfl_xor(tot, off, 64);
        if (lane == 0) wred[wave] = tot;
        __syncthreads();
        if (threadIdx.x == 0) {
            float v = 0.f;
            for (int w = 0; w < 16; ++w) v += wred[w];
            cohStore(&partials[blk], v);
        }
    }

    barrier_sync(gctr, GRID_BLOCKS);

    if (blk == 0) {
        float v = (threadIdx.x < GRID_BLOCKS) ? cohLoad(&partials[threadIdx.x]) : 0.f;
        for (int off = 1; off < 64; off <<= 1) v += __shfl_xor(v, off, 64);
        if (lane == 0) wred[wave] = v;
        __syncthreads();
        if (threadIdx.x == 0) {
            float t2 = 0.f;
            for (int w = 0; w < 16; ++w) t2 += wred[w];
            out[0] = t2 * (1.0f / BB);
        }
    }
}

extern "C" void kernel_launch(void* const* d_in, const int* in_sizes, int n_in,
                              void* d_out, int out_size, void* d_ws, size_t ws_size,
                              hipStream_t stream) {
    const float* preds = (const float*)d_in[0];
    const float* gts   = (const float*)d_in[1];
    float* fp       = (float*)d_ws;
    float* gp       = fp + BB * NN;
    float* partials = gp + BB * NN;
    int*   bctr     = (int*)(partials + GRID_BLOCKS);
    int*   gctr     = bctr + BB * 32;
    float* out      = (float*)d_out;

    size_t zbytes = (size_t)(2 * BB * NN + GRID_BLOCKS) * sizeof(float)
                  + (size_t)(BB * 32 + 32) * sizeof(int);
    (void)hipMemsetAsync(d_ws, 0, zbytes, stream);

    emd_persist<<<dim3(GRID_BLOCKS), dim3(TPB), 0, stream>>>(
        preds, gts, fp, gp, partials, bctr, gctr, out);
}

// Round 6
// 442.198 us; speedup vs baseline: 2.1514x; 2.1514x over previous
//
#include <hip/hip_runtime.h>

// Sinkhorn EMD, B=8, N=2048, eps=0.005, 50 iters.
// R24 = R18 champion (500.4us measured, VGPR 60, FETCH 3.8MB) + ONE
// change: the wave's 4 row-pot stores coalesced from 4 scalar lane-0
// cohStores (4x32B sectors, WRITE 52MB measured) into one store issued
// by lanes 0..3 at consecutive addresses (1x32B sector, same proven
// 32-bit plain-store path). All lanes hold L[r] post-butterfly, so
// lanes 1..3 store correct values.
// ABANDONED after R21/R22/R23 (716/732/951us): register-cached sparse
// lists — VGPR_Count stayed 64 in all three variants (X/J cache never
// left scratch; FETCH 45-73MB of scratch traffic). Do not retry blind.
// Structure (all validated): persistent 256x1024, IC-coherent atomics
// no fences (R6), register-resident row state + per-row sparse gathers
// w/ direct IC pot loads (R12), counter barrier (R3), online exact-LSE
// passes 0..3, build at {4,5}, fixed-shift M = own prev log-sum,
// MARGIN=48, CAP=256 (R9/R16).

#define BB 8
#define NN 2048
#define NPASS 100
#define ONLINE_PASSES 4
#define RPW 4
#define GRID_BLOCKS 256
#define BLOCKS_PER_BATCH 32
#define TPB 1024
#define CAP 256
#define MARGIN 48.0f

constexpr float EPSV = 0.005f;
constexpr float KS   = EPSV * 0.69314718055994531f; // eps*ln2
constexpr float INVK = 1.0f / KS;
constexpr float C1V  = -EPSV * 7.6246189861593985f; // eps*log(1/2048)
constexpr float C1K  = C1V * INVK;
constexpr float KQ4  = KS * 0.25f;
constexpr float TWOI = 2.0f * INVK;
constexpr float HK   = KS * 0.5f;

__device__ __forceinline__ float fexp2(float x) { return __builtin_amdgcn_exp2f(x); }
__device__ __forceinline__ float flog2(float x) { return __builtin_amdgcn_logf(x); }

__device__ __forceinline__ float cohLoad(const float* p) {
    return __hip_atomic_load(p, __ATOMIC_RELAXED, __HIP_MEMORY_SCOPE_AGENT);
}
__device__ __forceinline__ void cohStore(float* p, float v) {
    __hip_atomic_store(p, v, __ATOMIC_RELAXED, __HIP_MEMORY_SCOPE_AGENT);
}
// 4 consecutive row-pots stored by lanes 0..3 as ONE wave instruction:
// 4x4B contiguous = one 32B sector (was 4 sectors from 4 lane-0 stores).
__device__ __forceinline__ void potStore4(float* p, int lane,
                                          float o0, float o1, float o2, float o3) {
    if (lane < 4) {
        float ov = (lane == 0) ? o0 : (lane == 1) ? o1 : (lane == 2) ? o2 : o3;
        cohStore(p + lane, ov);
    }
}

__device__ __forceinline__ void barrier_sync(int* ctr, int target) {
    __syncthreads();   // drains vmcnt: all waves' cohStores acked at IC
    if (threadIdx.x == 0) {
        __hip_atomic_fetch_add(ctr, 1, __ATOMIC_RELAXED, __HIP_MEMORY_SCOPE_AGENT);
        while (__hip_atomic_load(ctr, __ATOMIC_RELAXED, __HIP_MEMORY_SCOPE_AGENT) < target) {
            __builtin_amdgcn_s_sleep(1);
        }
    }
    __syncthreads();
}

__global__ void __launch_bounds__(TPB, 4) emd_persist(
    const float* __restrict__ preds, const float* __restrict__ gts,
    float* __restrict__ fpot, float* __restrict__ gpot,
    float* __restrict__ partials, int* __restrict__ bctr, int* __restrict__ gctr,
    float* __restrict__ out)
{
    __shared__ float4 sjall[2 * NN];          // side0=gts, side1=preds
    __shared__ float  sa[NN];                 // staged pots (dense passes only)
    __shared__ float  wred[16];
    __shared__ unsigned short slist[2][64][CAP];

    const int blk  = blockIdx.x;
    const int b    = blk & 7;
    const int rb   = blk >> 3;
    const int wave = threadIdx.x >> 6;
    const int lane = threadIdx.x & 63;
    const int rowL0 = wave * RPW;             // 0..60
    const int row0  = rb * 64 + rowL0;        // global row base for this wave

    const float* pb  = preds + (size_t)b * NN * 3;
    const float* gbp = gts   + (size_t)b * NN * 3;
    float* fb = fpot + (size_t)b * NN;
    float* gb = gpot + (size_t)b * NN;
    int*   bar = bctr + b * 32;

    for (int t = threadIdx.x; t < NN; t += TPB) {
        float gx = gbp[3*t], gy = gbp[3*t+1], gz = gbp[3*t+2];
        float Gx = gx*TWOI, Gy = gy*TWOI, Gz = gz*TWOI;
        sjall[t] = make_float4(Gx, Gy, Gz, -KQ4*(Gx*Gx+Gy*Gy+Gz*Gz));
        float qx = pb[3*t], qy = pb[3*t+1], qz = pb[3*t+2];
        float Qx = qx*TWOI, Qy = qy*TWOI, Qz = qz*TWOI;
        sjall[NN+t] = make_float4(Qx, Qy, Qz, -KQ4*(Qx*Qx+Qy*Qy+Qz*Qz));
    }
    __syncthreads();

    // wave-resident row constants, both sides (loaded ONCE)
    float qxf[RPW], qyf[RPW], qzf[RPW], pcf[RPW];
    float qxg[RPW], qyg[RPW], qzg[RPW], pcg[RPW];
#pragma unroll
    for (int r = 0; r < RPW; ++r) {
        float4 df = sjall[NN + row0 + r];     // preds rows (f side)
        qxf[r] = HK*df.x; qyf[r] = HK*df.y; qzf[r] = HK*df.z;
        pcf[r] = C1V - KS*df.w;
        float4 dg = sjall[row0 + r];          // gts rows (g side)
        qxg[r] = HK*dg.x; qyg[r] = HK*dg.y; qzg[r] = HK*dg.z;
        pcg[r] = C1V - KS*dg.w;
    }
    float LpF[RPW] = {0,0,0,0}, LpG[RPW] = {0,0,0,0};
    int   cnF[RPW] = {0,0,0,0}, cnG[RPW] = {0,0,0,0};

#pragma unroll 1
    for (int pass = 0; pass < NPASS; ++pass) {
        const int odd = pass & 1;
        const int colOff = odd ? NN : 0;
        const float* pin  = odd ? fb : gb;
        float*       pout = odd ? gb : fb;
        const bool isBuild  = (pass == 4) || (pass == 5);
        const bool isSparse = (pass >= ONLINE_PASSES) && !isBuild;

        float qx[RPW], qy[RPW], qz[RPW], pc[RPW], M[RPW];
#pragma unroll
        for (int r = 0; r < RPW; ++r) {
            qx[r] = odd ? qxg[r] : qxf[r];
            qy[r] = odd ? qyg[r] : qyf[r];
            qz[r] = odd ? qzg[r] : qzf[r];
            pc[r] = odd ? pcg[r] : pcf[r];
            M[r]  = odd ? LpG[r] : LpF[r];
        }

        if (isSparse) {
            // ---- sparse: no staging, no intra-pass sync ----
            float L[RPW];
#pragma unroll
            for (int r = 0; r < RPW; ++r) {
                const int cnt = odd ? cnG[r] : cnF[r];
                const unsigned short* lb = slist[odd][rowL0 + r];
                float s1 = 0.f;
                if (cnt <= CAP) {
#pragma unroll 1
                    for (int k = lane; k < cnt; k += 64) {
                        int j = lb[k];
                        float4 d = sjall[colOff + j];
                        float aw = fmaf(cohLoad(&pin[j]), INVK, d.w);
                        float x  = fmaf(qx[r], d.x, fmaf(qy[r], d.y, fmaf(qz[r], d.z, aw)));
                        s1 += fexp2(fminf(x - M[r], 100.f));
                    }
                } else {
#pragma unroll 1
                    for (int c = 0; c < 32; ++c) {
                        int j = c*64 + lane;
                        float4 d = sjall[colOff + j];
                        float aw = fmaf(cohLoad(&pin[j]), INVK, d.w);
                        float x  = fmaf(qx[r], d.x, fmaf(qy[r], d.y, fmaf(qz[r], d.z, aw)));
                        s1 += fexp2(fminf(x - M[r], 100.f));
                    }
                }
                for (int off = 1; off < 64; off <<= 1) s1 += __shfl_xor(s1, off, 64);
                L[r] = M[r] + flog2(fmaxf(s1, 1e-37f));
            }
#pragma unroll
            for (int r = 0; r < RPW; ++r) {
                if (odd) LpG[r] = L[r]; else LpF[r] = L[r];
            }
            potStore4(&pout[row0], lane, pc[0]-KS*L[0], pc[1]-KS*L[1],
                                         pc[2]-KS*L[2], pc[3]-KS*L[3]);
        } else {
            // ---- dense-type: stage sa, full sweep ----
            for (int t = threadIdx.x; t < NN; t += TPB)
                sa[t] = cohLoad(&pin[t]) * INVK;
            __syncthreads();

            if (pass < ONLINE_PASSES) {
                float m[RPW], s[RPW], Lr[RPW];
#pragma unroll
                for (int r = 0; r < RPW; ++r) { m[r] = -1e30f; s[r] = 0.f; }
#pragma unroll 2
                for (int c = 0; c < 32; ++c) {
                    float4 d = sjall[colOff + c*64 + lane];
                    float aw = d.w + sa[c*64 + lane];
#pragma unroll
                    for (int r = 0; r < RPW; ++r) {
                        float x  = fmaf(qx[r], d.x, fmaf(qy[r], d.y, fmaf(qz[r], d.z, aw)));
                        float mn = fmaxf(m[r], x);
                        s[r] = fmaf(s[r], fexp2(m[r]-mn), fexp2(x-mn));
                        m[r] = mn;
                    }
                }
#pragma unroll
                for (int r = 0; r < RPW; ++r) {
                    float mm = m[r], sv = s[r];
                    for (int off = 1; off < 64; off <<= 1) {
                        float mo = __shfl_xor(mm, off, 64);
                        float so = __shfl_xor(sv, off, 64);
                        float mn = fmaxf(mm, mo);
                        sv = fmaf(sv, fexp2(mm-mn), so * fexp2(mo-mn));
                        mm = mn;
                    }
                    float L = mm + flog2(fmaxf(sv, 1e-37f));
                    Lr[r] = L;
                    if (odd) LpG[r] = L; else LpF[r] = L;
                }
                potStore4(&pout[row0], lane, pc[0]-KS*Lr[0], pc[1]-KS*Lr[1],
                                             pc[2]-KS*Lr[2], pc[3]-KS*Lr[3]);
            } else {
                // build: dense fixed-shift + register-count compaction
                float s[RPW], Lr[RPW]; int cn[RPW];
#pragma unroll
                for (int r = 0; r < RPW; ++r) { s[r] = 0.f; cn[r] = 0; }
#pragma unroll 1
                for (int c = 0; c < 32; ++c) {
                    int j = c*64 + lane;
                    float4 d = sjall[colOff + j];
                    float aw = d.w + sa[j];
#pragma unroll
                    for (int r = 0; r < RPW; ++r) {
                        float x = fmaf(qx[r], d.x, fmaf(qy[r], d.y, fmaf(qz[r], d.z, aw)));
                        s[r] += fexp2(fminf(x - M[r], 100.f));
                        bool pred = (x >= M[r] - MARGIN);
                        unsigned long long mask = __ballot((int)pred);
                        if (pred) {
                            int pos = cn[r] + __popcll(mask & ((1ull << lane) - 1ull));
                            if (pos < CAP) slist[odd][rowL0 + r][pos] = (unsigned short)j;
                        }
                        cn[r] += __popcll(mask);   // wave-uniform
                    }
                }
#pragma unroll
                for (int r = 0; r < RPW; ++r) {
                    float sv = s[r];
                    for (int off = 1; off < 64; off <<= 1) sv += __shfl_xor(sv, off, 64);
                    float L = M[r] + flog2(fmaxf(sv, 1e-37f));
                    Lr[r] = L;
                    if (odd) { LpG[r] = L; cnG[r] = cn[r]; }
                    else     { LpF[r] = L; cnF[r] = cn[r]; }
                }
                potStore4(&pout[row0], lane, pc[0]-KS*Lr[0], pc[1]-KS*Lr[1],
                                             pc[2]-KS*Lr[2], pc[3]-KS*Lr[3]);
            }
        }
        barrier_sync(bar, BLOCKS_PER_BATCH * (pass + 1));
    }

    // ---- dis: sum P*C over f-lists (side 0), direct pot loads ----
    {
        float acc[RPW];
#pragma unroll
        for (int r = 0; r < RPW; ++r) acc[r] = 0.f;
#pragma unroll
        for (int r = 0; r < RPW; ++r) {
            const int cnt = cnF[r];
            const unsigned short* lb = slist[0][rowL0 + r];
            const float bb2 = C1K - LpF[r];
            const float pn  = pcf[r] - C1V;    // |p|^2
            float aa = 0.f;
            if (cnt <= CAP) {
#pragma unroll 1
                for (int k = lane; k < cnt; k += 64) {
                    int j = lb[k];
                    float4 d = sjall[j];
                    float aw = fmaf(cohLoad(&gb[j]), INVK, d.w);
                    float dot = fmaf(qxf[r], d.x, fmaf(qyf[r], d.y, qzf[r]*d.z));
                    float y   = dot + aw + bb2;
                    float e   = fexp2(fminf(y, 80.f));
                    aa = fmaf(e, fmaf(-KS, dot, pn - KS*d.w), aa);
                }
            } else {
#pragma unroll 1
                for (int c = 0; c < 32; ++c) {
                    int j = c*64 + lane;
                    float4 d = sjall[j];
                    float aw = fmaf(cohLoad(&gb[j]), INVK, d.w);
                    float dot = fmaf(qxf[r], d.x, fmaf(qyf[r], d.y, qzf[r]*d.z));
                    float y   = dot + aw + bb2;
                    float e   = fexp2(fminf(y, 80.f));
                    aa = fmaf(e, fmaf(-KS, dot, pn - KS*d.w), aa);
                }
            }
            acc[r] = aa;
        }
        float tot = acc[0] + acc[1] + acc[2] + acc[3];
        for (int off = 1; off < 64; off <<= 1) tot += __shfl_xor(tot, off, 64);
        if (lane == 0) wred[wave] = tot;
        __syncthreads();
        if (threadIdx.x == 0) {
            float v = 0.f;
            for (int w = 0; w < 16; ++w) v += wred[w];
            cohStore(&partials[blk], v);
        }
    }

    barrier_sync(gctr, GRID_BLOCKS);

    if (blk == 0) {
        float v = (threadIdx.x < GRID_BLOCKS) ? cohLoad(&partials[threadIdx.x]) : 0.f;
        for (int off = 1; off < 64; off <<= 1) v += __shfl_xor(v, off, 64);
        if (lane == 0) wred[wave] = v;
        __syncthreads();
        if (threadIdx.x == 0) {
            float t2 = 0.f;
            for (int w = 0; w < 16; ++w) t2 += wred[w];
            out[0] = t2 * (1.0f / BB);
        }
    }
}

extern "C" void kernel_launch(void* const* d_in, const int* in_sizes, int n_in,
                              void* d_out, int out_size, void* d_ws, size_t ws_size,
                              hipStream_t stream) {
    const float* preds = (const float*)d_in[0];
    const float* gts   = (const float*)d_in[1];
    float* fp       = (float*)d_ws;
    float* gp       = fp + BB * NN;
    float* partials = gp + BB * NN;
    int*   bctr     = (int*)(partials + GRID_BLOCKS);
    int*   gctr     = bctr + BB * 32;
    float* out      = (float*)d_out;

    size_t zbytes = (size_t)(2 * BB * NN + GRID_BLOCKS) * sizeof(float)
                  + (size_t)(BB * 32 + 32) * sizeof(int);
    (void)hipMemsetAsync(d_ws, 0, zbytes, stream);

    emd_persist<<<dim3(GRID_BLOCKS), dim3(TPB), 0, stream>>>(
        preds, gts, fp, gp, partials, bctr, gctr, out);
}